// Round 19
// baseline (355.445 us; speedup 1.0000x reference)
//
#include <hip/hip_runtime.h>
#include <hip/hip_bf16.h>

// CrossBandWindowAttentionWav — R19 = R12 GEMMs + dual-window ap_k.
// ap_k processes 2 windows/block (grid 1024): attention w0 -> stash0 (regs),
// attention w1 -> stash1, then ONE proj pass whose 24 B-tile drains serve
// both windows (24 MFMA per drain vs 12). att spill eliminated via R16's
// verified per-kt stash->Pr wave-private handoff (kt-inner FULLY UNROLLED so
// all stash indices are static — R17's spill was runtime-kt indexing).
// LDS 56KB: vt 48K @0 (B dbuf 24K + Pr1 8K overlay in proj) | P/Pr0 8K @49152.

typedef __attribute__((ext_vector_type(8))) short short8;
typedef __attribute__((ext_vector_type(4))) float f32x4;

__device__ __forceinline__ f32x4 mfma_b16(short8 a, short8 b, f32x4 c) {
  return __builtin_amdgcn_mfma_f32_16x16x32_bf16(a, b, c, 0, 0, 0);
}

__device__ __forceinline__ unsigned short f2bf(float x) {
  return __builtin_bit_cast(unsigned short, __float2bfloat16(x));  // RNE
}

__device__ __forceinline__ unsigned pack2(float a, float b) {
  return (unsigned)f2bf(a) | ((unsigned)f2bf(b) << 16);
}

// chunk swizzle for 768B rows (48 x 16B chunks): XOR low3 of chunk with row
__device__ __forceinline__ int swz48(int c, int r) {
  return (c & ~7) | ((c ^ r) & 7);
}

__device__ __forceinline__ void gl_lds16(const char* g, char* l) {
  __builtin_amdgcn_global_load_lds(
      (const __attribute__((address_space(1))) unsigned int*)g,
      (__attribute__((address_space(3))) unsigned int*)l, 16, 0, 0);
}

// ---------------------------------------------------------------- prep ------
__global__ void prep_k(const float* __restrict__ Wq, const float* __restrict__ Wk,
                       const float* __restrict__ Wv, const float* __restrict__ Wp,
                       const float* __restrict__ rpb, const int* __restrict__ rpi,
                       const float* __restrict__ bk, const float* __restrict__ bv,
                       unsigned short* __restrict__ Wq_t, unsigned short* __restrict__ Wkv_t,
                       unsigned short* __restrict__ Wp_t, float* __restrict__ bias6,
                       float* __restrict__ bias_kv) {
  const int T0 = 96 * 384, T1 = 480 * 384, T2 = 384 * 384, T3 = 6 * 4096, T4 = 480;
  int total = T0 + T1 + T2 + T3 + T4;
  for (int i = blockIdx.x * blockDim.x + threadIdx.x; i < total;
       i += gridDim.x * blockDim.x) {
    int r = i;
    if (r < T0) {                       // Wq_t[n][k] = Wq[k][n]
      int n = r / 384, k = r % 384;
      Wq_t[r] = f2bf(Wq[k * 96 + n]);
    } else if ((r -= T0) < T1) {        // rows 0..95 = Wk^T, 96..479 = Wv^T
      int n = r / 384, k = r % 384;
      Wkv_t[r] = f2bf(n < 96 ? Wk[k * 96 + n] : Wv[k * 384 + (n - 96)]);
    } else if ((r -= T1) < T2) {
      int n = r / 384, k = r % 384;
      Wp_t[r] = f2bf(Wp[k * 384 + n]);
    } else if ((r -= T2) < T3) {        // bias6[h][i][j] = rpb[rpi[i][j]][h]
      int h = r >> 12, ij = r & 4095;
      bias6[r] = rpb[rpi[ij] * 6 + h];
    } else {
      r -= T3;
      bias_kv[r] = (r < 96) ? bk[r] : bv[r - 96];
    }
  }
}

// ---------------------------------------------------------------- GEMM ------
// R12-proven gemm3_k. C[M=131072, N=NX*96] = A[M,384] @ Bt[N,384]^T + bias.
// BM=64 BN=96 BK=64, 40KB LDS dbuf, 4 blocks/CU, XCD-bijective swizzle.
// OUT_MODE 0: bf16 [M,96] | 2: nx==0 -> k_out[M,96]; nx>=1 -> vt_out
// (win,d,tok) bf16 with PRE-SWIZZLED 16B chunks (c ^ (d&7)).
template <int A_MODE, int OUT_MODE, int NX>
__global__ __launch_bounds__(256, 4) void gemm3_k(
    const void* __restrict__ Av, const unsigned short* __restrict__ Bt,
    const float* __restrict__ bias, void* __restrict__ Outv,
    unsigned short* __restrict__ k_out, unsigned short* __restrict__ vt_out) {
  __shared__ char lds[40960];  // A: 2x8KB @0, B: 2x12KB @16384
  constexpr int AB[2] = {0, 8192}, BB[2] = {16384, 28672};
  const int tid = threadIdx.x, lane = tid & 63, wid = tid >> 6;
  const int g = blockIdx.x;
  const int lg_id = (g & 7) * (NX * 256) + (g >> 3);
  const int my = lg_id / NX, nx = lg_id - my * NX;
  const int m0 = my * 64, n0 = nx * 96;
  const int wm = (wid >> 1) * 32, wn = (wid & 1) * 48;
  const int lr = lane & 15, lg = lane >> 4;

  float4 areg[4];
  const int ar = tid >> 2, aq = tid & 3;  // fp32-A staging: row, quarter

  auto a_issue_f32 = [&](int kt) {
    const float* A = (const float*)Av + (size_t)(m0 + ar) * 384 + kt * 64 + aq * 16;
#pragma unroll
    for (int p = 0; p < 4; ++p) areg[p] = *reinterpret_cast<const float4*>(A + p * 4);
  };
  auto a_write_f32 = [&](char* Ab) {
    unsigned pk[8];
#pragma unroll
    for (int p = 0; p < 4; ++p) {
      pk[p * 2]     = pack2(areg[p].x, areg[p].y);
      pk[p * 2 + 1] = pack2(areg[p].z, areg[p].w);
    }
    const int c0 = aq * 2;
    *reinterpret_cast<uint4*>(Ab + ar * 128 + ((c0 ^ (ar & 7)) * 16)) =
        make_uint4(pk[0], pk[1], pk[2], pk[3]);
    *reinterpret_cast<uint4*>(Ab + ar * 128 + (((c0 + 1) ^ (ar & 7)) * 16)) =
        make_uint4(pk[4], pk[5], pk[6], pk[7]);
  };
  auto b_issue = [&](int kt, char* Bb) {
#pragma unroll
    for (int j = 0; j < 3; ++j) {
      const int rb = (wid * 3 + j) * 8;
      const int row = rb + (lane >> 3), c = lane & 7;
      gl_lds16((const char*)Bt + (size_t)(n0 + row) * 768 + kt * 128 +
                   ((c ^ (row & 7)) * 16),
               Bb + rb * 128);
    }
  };

  f32x4 acc[2][3];
#pragma unroll
  for (int i = 0; i < 2; ++i)
#pragma unroll
    for (int j = 0; j < 3; ++j) acc[i][j] = (f32x4){0.f, 0.f, 0.f, 0.f};

  a_issue_f32(0);
  a_write_f32(lds + AB[0]);
  b_issue(0, lds + BB[0]);
  __syncthreads();

  int cur = 0;
  for (int kt = 0; kt < 6; ++kt) {
    char* An = lds + AB[cur ^ 1];
    char* Bn = lds + BB[cur ^ 1];
    if (kt < 5) {
      a_issue_f32(kt + 1);
      b_issue(kt + 1, Bn);
    }
    {
      const char* Ab = lds + AB[cur];
      const char* Bb = lds + BB[cur];
#pragma unroll
      for (int ks = 0; ks < 2; ++ks) {
        short8 a[2], b[3];
#pragma unroll
        for (int mf = 0; mf < 2; ++mf) {
          const int row = wm + mf * 16 + lr;
          a[mf] = *reinterpret_cast<const short8*>(
              Ab + row * 128 + (((ks * 4 + lg) ^ (row & 7)) * 16));
        }
#pragma unroll
        for (int nf = 0; nf < 3; ++nf) {
          const int row = wn + nf * 16 + lr;
          b[nf] = *reinterpret_cast<const short8*>(
              Bb + row * 128 + (((ks * 4 + lg) ^ (row & 7)) * 16));
        }
#pragma unroll
        for (int mf = 0; mf < 2; ++mf)
#pragma unroll
          for (int nf = 0; nf < 3; ++nf)
            acc[mf][nf] = mfma_b16(a[mf], b[nf], acc[mf][nf]);
      }
    }
    if (kt < 5) a_write_f32(An);
    __syncthreads();
    cur ^= 1;
  }

  // ---- epilogues
  if (OUT_MODE == 0 || (OUT_MODE == 2 && nx == 0)) {  // bf16 [M,96], pad 208
    unsigned short* dst = (OUT_MODE == 0) ? (unsigned short*)Outv : k_out;
#pragma unroll
    for (int mf = 0; mf < 2; ++mf)
#pragma unroll
      for (int nf = 0; nf < 3; ++nf) {
        const int col = wn + nf * 16 + lr;
        const float bb = bias[col];
#pragma unroll
        for (int r = 0; r < 4; ++r) {
          const int row = wm + mf * 16 + lg * 4 + r;
          *reinterpret_cast<unsigned short*>(lds + row * 208 + col * 2) =
              f2bf(acc[mf][nf][r] + bb);
        }
      }
    __syncthreads();
#pragma unroll
    for (int j = 0; j < 3; ++j) {
      const int Lb = (j * 256 + tid) * 16;
      const int row = Lb / 192, inner = Lb % 192;
      *reinterpret_cast<uint4*>((char*)dst + (size_t)(m0 + row) * 192 + inner) =
          *reinterpret_cast<const uint4*>(lds + row * 208 + inner);
    }
  } else {  // vt: transpose to (win=my, d, tok), PRE-SWIZZLED chunks
#pragma unroll
    for (int mf = 0; mf < 2; ++mf)
#pragma unroll
      for (int nf = 0; nf < 3; ++nf) {
        const int dl = wn + nf * 16 + lr;
        const float bb = bias[n0 + dl];
        const int tok0 = wm + mf * 16 + lg * 4;
        *reinterpret_cast<unsigned*>(lds + dl * 144 + tok0 * 2) =
            pack2(acc[mf][nf][0] + bb, acc[mf][nf][1] + bb);
        *reinterpret_cast<unsigned*>(lds + dl * 144 + tok0 * 2 + 4) =
            pack2(acc[mf][nf][2] + bb, acc[mf][nf][3] + bb);
      }
    __syncthreads();
#pragma unroll
    for (int j = 0; j < 3; ++j) {
      const int Lc = j * 256 + tid;  // 16B chunk id, 768 total
      const int dl = Lc >> 3, c = Lc & 7;
      *reinterpret_cast<uint4*>((char*)vt_out + (size_t)my * 49152 +
                                (size_t)((nx - 1) * 96 + dl) * 128 +
                                ((c ^ (dl & 7)) << 4)) =
          *reinterpret_cast<const uint4*>(lds + dl * 144 + c * 16);
    }
  }
}

// ------------------------------- fused dual-window attention + proj ---------
// 1 block = 2 windows, 4 waves, 56KB LDS, 2 blocks/CU, grid 1024.
__global__ __launch_bounds__(256, 2) void ap_k(
    const unsigned short* __restrict__ q_buf, const unsigned short* __restrict__ k_buf,
    const unsigned short* __restrict__ vt_buf, const float* __restrict__ bias6,
    const float* __restrict__ mask, const unsigned short* __restrict__ Wp_t,
    const float* __restrict__ bp, float* __restrict__ out) {
  __shared__ char lds[57344];
  const int tid = threadIdx.x, lane = tid & 63, wid = tid >> 6;
  const int lr = lane & 15, lg = lane >> 4;
  const int w0 = blockIdx.x * 2;
  const int iq = wid * 16 + lr;
  char* P0 = lds + 49152;   // attn P / proj Pr for w0
  char* P1 = lds + 24576;   // proj Pr for w1 (dead vt region)

  auto stage_vt = [&](int w) {
    const char* vsrc = (const char*)vt_buf + (size_t)w * 49152;
#pragma unroll
    for (int j = 0; j < 12; ++j) {
      const int off = (wid * 12 + j) * 1024;
      gl_lds16(vsrc + off + lane * 16, lds + off);
    }
  };
  auto b_issue = [&](int nc, int kt, char* Bb) {
#pragma unroll
    for (int j = 0; j < 3; ++j) {
      const int rb = (wid * 3 + j) * 8;
      const int row = rb + (lane >> 3), c = lane & 7;
      gl_lds16((const char*)Wp_t + (size_t)(nc * 96 + row) * 768 + kt * 128 +
                   ((c ^ (row & 7)) * 16),
               Bb + rb * 128);
    }
  };

  unsigned stash0[48], stash1[48];
  const float* mw0 = mask + (size_t)(w0 & 1023) * 4096;
  const float* mw1 = mask + (size_t)((w0 + 1) & 1023) * 4096;

  // R12-proven attention for one window (vt in lds[0,48K), P = P0)
  auto attn_phase = [&](int w, const float* mw, unsigned (&st)[48]) {
#pragma unroll
    for (int h = 0; h < 6; ++h) {
      short8 qa = {0, 0, 0, 0, 0, 0, 0, 0};
      if (lg < 2)
        qa = *reinterpret_cast<const short8*>(
            q_buf + (size_t)(w * 64 + iq) * 96 + h * 16 + lg * 8);
      float sv[4][4];
#pragma unroll
      for (int tj = 0; tj < 4; ++tj) {
        short8 kf = {0, 0, 0, 0, 0, 0, 0, 0};
        if (lg < 2)
          kf = *reinterpret_cast<const short8*>(
              k_buf + (size_t)(w * 64 + tj * 16 + lr) * 96 + h * 16 + lg * 8);
        f32x4 z = {0.f, 0.f, 0.f, 0.f};
        f32x4 s = mfma_b16(kf, qa, z);
        const int j0 = tj * 16 + lg * 4;
        const float4 bi =
            *reinterpret_cast<const float4*>(bias6 + h * 4096 + iq * 64 + j0);
        const float4 mk = *reinterpret_cast<const float4*>(mw + iq * 64 + j0);
        sv[tj][0] = s[0] * 0.25f + bi.x + mk.x;
        sv[tj][1] = s[1] * 0.25f + bi.y + mk.y;
        sv[tj][2] = s[2] * 0.25f + bi.z + mk.z;
        sv[tj][3] = s[3] * 0.25f + bi.w + mk.w;
      }
      float mx = sv[0][0];
#pragma unroll
      for (int tj = 0; tj < 4; ++tj)
#pragma unroll
        for (int r = 0; r < 4; ++r) mx = fmaxf(mx, sv[tj][r]);
      mx = fmaxf(mx, __shfl_xor(mx, 16));
      mx = fmaxf(mx, __shfl_xor(mx, 32));
      float sum = 0.f;
#pragma unroll
      for (int tj = 0; tj < 4; ++tj)
#pragma unroll
        for (int r = 0; r < 4; ++r) {
          sv[tj][r] = __expf(sv[tj][r] - mx);
          sum += sv[tj][r];
        }
      sum += __shfl_xor(sum, 16);
      sum += __shfl_xor(sum, 32);
      const float inv = 1.0f / sum;
#pragma unroll
      for (int tj = 0; tj < 4; ++tj) {
        const int c = tj * 2 + (lg >> 1);
        uint2 st2;
        st2.x = pack2(sv[tj][0] * inv, sv[tj][1] * inv);
        st2.y = pack2(sv[tj][2] * inv, sv[tj][3] * inv);
        *reinterpret_cast<uint2*>(P0 + iq * 128 + ((c ^ (iq & 7)) << 4) +
                                  (lg & 1) * 8) = st2;
      }
      short8 pa[2];
#pragma unroll
      for (int ks = 0; ks < 2; ++ks)
        pa[ks] = *reinterpret_cast<const short8*>(
            P0 + iq * 128 + (((ks * 4 + lg) ^ (iq & 7)) << 4));
#pragma unroll
      for (int td = 0; td < 4; ++td) {
        f32x4 o = {0.f, 0.f, 0.f, 0.f};
#pragma unroll
        for (int ks = 0; ks < 2; ++ks) {
          const int d = h * 64 + td * 16 + lr;
          short8 vb = *reinterpret_cast<const short8*>(
              lds + d * 128 + (((ks * 4 + lg) ^ (d & 7)) << 4));
          o = mfma_b16(vb, pa[ks], o);
        }
        st[h * 8 + td * 2 + 0] = pack2(o[0], o[1]);
        st[h * 8 + td * 2 + 1] = pack2(o[2], o[3]);
      }
    }
  };

  // ---- window 0
  stage_vt(w0);
  __syncthreads();
  attn_phase(w0, mw0, stash0);
  __syncthreads();  // vt(w0) reads done
  // ---- window 1
  stage_vt(w0 + 1);
  __syncthreads();
  attn_phase(w0 + 1, mw1, stash1);
  __syncthreads();  // vt(w1) reads done; [0,48K) region now free for B/Pr1

  // ---- proj: both windows share each B tile. nc outer (runtime, addresses
  // only), kt inner FULLY UNROLLED (static stash/acc indices — no scratch).
  b_issue(0, 0, lds);
  __syncthreads();  // B(0,0) landed+visible

#pragma unroll 1
  for (int nc = 0; nc < 4; ++nc) {
    f32x4 acc0[6], acc1[6];
#pragma unroll
    for (int j = 0; j < 6; ++j) {
      acc0[j] = (f32x4){0.f, 0.f, 0.f, 0.f};
      acc1[j] = (f32x4){0.f, 0.f, 0.f, 0.f};
    }
#pragma unroll
    for (int kt = 0; kt < 6; ++kt) {
      if (kt < 5) b_issue(nc, kt + 1, lds + ((kt + 1) & 1) * 12288);
      else if (nc < 3) b_issue(nc + 1, 0, lds);  // parity: next is buf 0
      const char* Bb = lds + (kt & 1) * 12288;
      // handoff (wave-private; kt static): stash block kt -> Pr rows iq
#pragma unroll
      for (int td = 0; td < 4; ++td) {
        uint2 s0 = make_uint2(stash0[kt * 8 + td * 2], stash0[kt * 8 + td * 2 + 1]);
        uint2 s1 = make_uint2(stash1[kt * 8 + td * 2], stash1[kt * 8 + td * 2 + 1]);
        const int off = iq * 128 + (((td * 2 + (lg >> 1)) ^ (iq & 7)) << 4) +
                        (lg & 1) * 8;
        *reinterpret_cast<uint2*>(P0 + off) = s0;
        *reinterpret_cast<uint2*>(P1 + off) = s1;
      }
      short8 a00 = *reinterpret_cast<const short8*>(
          P0 + iq * 128 + (((0 + lg) ^ (iq & 7)) << 4));
      short8 a01 = *reinterpret_cast<const short8*>(
          P0 + iq * 128 + (((4 + lg) ^ (iq & 7)) << 4));
      short8 a10 = *reinterpret_cast<const short8*>(
          P1 + iq * 128 + (((0 + lg) ^ (iq & 7)) << 4));
      short8 a11 = *reinterpret_cast<const short8*>(
          P1 + iq * 128 + (((4 + lg) ^ (iq & 7)) << 4));
      __builtin_amdgcn_s_setprio(1);
#pragma unroll
      for (int ks = 0; ks < 2; ++ks) {
        const short8 a0 = ks ? a01 : a00;
        const short8 a1 = ks ? a11 : a10;
#pragma unroll
        for (int nf = 0; nf < 6; ++nf) {
          const int row = nf * 16 + lr;
          const short8 b = *reinterpret_cast<const short8*>(
              Bb + row * 128 + (((ks * 4 + lg) ^ (row & 7)) * 16));
          acc0[nf] = mfma_b16(a0, b, acc0[nf]);
          acc1[nf] = mfma_b16(a1, b, acc1[nf]);
        }
      }
      __builtin_amdgcn_s_setprio(0);
      if (kt == 5) {  // epilogue for this nc (before bottom sync)
#pragma unroll
        for (int nf = 0; nf < 6; ++nf) {
          const int col = nc * 96 + nf * 16 + lr;
          const float bb = bp[col];
#pragma unroll
          for (int r = 0; r < 4; ++r) {
            const int rowl = wid * 16 + lg * 4 + r;
            out[(size_t)(w0 * 64 + rowl) * 384 + col] = acc0[nf][r] + bb;
            out[(size_t)((w0 + 1) * 64 + rowl) * 384 + col] = acc1[nf][r] + bb;
          }
        }
      }
      __syncthreads();  // B(next) landed+visible; WAR for buffer reuse
    }
  }
}

// -------------------------------------------------------------- launch ------
extern "C" void kernel_launch(void* const* d_in, const int* in_sizes, int n_in,
                              void* d_out, int out_size, void* d_ws, size_t ws_size,
                              hipStream_t stream) {
  const float* x    = (const float*)d_in[0];
  const float* cx   = (const float*)d_in[1];
  const int*   rpi  = (const int*)d_in[2];
  const float* mask = (const float*)d_in[3];
  const float* Wq   = (const float*)d_in[4];
  const float* bq   = (const float*)d_in[5];
  const float* Wk   = (const float*)d_in[6];
  const float* bk   = (const float*)d_in[7];
  const float* Wv   = (const float*)d_in[8];
  const float* bv   = (const float*)d_in[9];
  const float* Wp   = (const float*)d_in[10];
  const float* bp   = (const float*)d_in[11];
  const float* rpb  = (const float*)d_in[12];

  char* ws = (char*)d_ws;
  unsigned short* Wq_t   = (unsigned short*)(ws + 0);        //  73,728 B
  unsigned short* Wkv_t  = (unsigned short*)(ws + 73728);    // 368,640 B
  unsigned short* Wp_t   = (unsigned short*)(ws + 442368);   // 294,912 B
  float*          bias6  = (float*)(ws + 737280);            //  98,304 B
  float*          biaskv = (float*)(ws + 835584);            //   1,920 B
  const size_t MB = 1u << 20;
  unsigned short* q_buf  = (unsigned short*)(ws + MB);                   // 25,165,824 B
  unsigned short* k_buf  = (unsigned short*)(ws + MB + 25165824u);       // 25,165,824 B
  unsigned short* vt_buf = (unsigned short*)(ws + MB + 50331648u);       // 100,663,296 B

  prep_k<<<256, 256, 0, stream>>>(Wq, Wk, Wv, Wp, rpb, rpi, bk, bv,
                                  Wq_t, Wkv_t, Wp_t, bias6, biaskv);
  gemm3_k<0, 0, 1><<<2048, 256, 0, stream>>>(x, Wq_t, bq, q_buf, nullptr, nullptr);
  gemm3_k<0, 2, 5><<<10240, 256, 0, stream>>>(cx, Wkv_t, biaskv, nullptr, k_buf, vt_buf);
  ap_k<<<1024, 256, 0, stream>>>(q_buf, k_buf, vt_buf, bias6, mask, Wp_t, bp,
                                 (float*)d_out);
}

// Round 20
// 347.852 us; speedup vs baseline: 1.0218x; 1.0218x over previous
//
#include <hip/hip_runtime.h>
#include <hip/hip_bf16.h>

// CrossBandWindowAttentionWav — R20 = R12/R18 verbatim (empirical optimum,
// 348us, reproduced twice). R13-R19 single-variable deviations all neutral or
// negative: counted-vmcnt x3 (race/neutral), input prefetch (neutral), higher
// occupancy (+14us), kt-outer (VGPR spill +30us), dual-window (+7us).
// Pipeline: prep -> gemm3 q -> gemm3 k|v (vt PRE-SWIZZLED chunks) -> ap_k
// fused attention+projection (att stays in regs/LDS, never HBM).
// 4 blk/CU GEMMs, XCD-bijective swizzle, global_load_lds staging.

typedef __attribute__((ext_vector_type(8))) short short8;
typedef __attribute__((ext_vector_type(4))) float f32x4;

__device__ __forceinline__ f32x4 mfma_b16(short8 a, short8 b, f32x4 c) {
  return __builtin_amdgcn_mfma_f32_16x16x32_bf16(a, b, c, 0, 0, 0);
}

__device__ __forceinline__ unsigned short f2bf(float x) {
  return __builtin_bit_cast(unsigned short, __float2bfloat16(x));  // RNE
}

__device__ __forceinline__ unsigned pack2(float a, float b) {
  return (unsigned)f2bf(a) | ((unsigned)f2bf(b) << 16);
}

// chunk swizzle for 768B rows (48 x 16B chunks): XOR low3 of chunk with row
__device__ __forceinline__ int swz48(int c, int r) {
  return (c & ~7) | ((c ^ r) & 7);
}

__device__ __forceinline__ void gl_lds16(const char* g, char* l) {
  __builtin_amdgcn_global_load_lds(
      (const __attribute__((address_space(1))) unsigned int*)g,
      (__attribute__((address_space(3))) unsigned int*)l, 16, 0, 0);
}

// ---------------------------------------------------------------- prep ------
__global__ void prep_k(const float* __restrict__ Wq, const float* __restrict__ Wk,
                       const float* __restrict__ Wv, const float* __restrict__ Wp,
                       const float* __restrict__ rpb, const int* __restrict__ rpi,
                       const float* __restrict__ bk, const float* __restrict__ bv,
                       unsigned short* __restrict__ Wq_t, unsigned short* __restrict__ Wkv_t,
                       unsigned short* __restrict__ Wp_t, float* __restrict__ bias6,
                       float* __restrict__ bias_kv) {
  const int T0 = 96 * 384, T1 = 480 * 384, T2 = 384 * 384, T3 = 6 * 4096, T4 = 480;
  int total = T0 + T1 + T2 + T3 + T4;
  for (int i = blockIdx.x * blockDim.x + threadIdx.x; i < total;
       i += gridDim.x * blockDim.x) {
    int r = i;
    if (r < T0) {                       // Wq_t[n][k] = Wq[k][n]
      int n = r / 384, k = r % 384;
      Wq_t[r] = f2bf(Wq[k * 96 + n]);
    } else if ((r -= T0) < T1) {        // rows 0..95 = Wk^T, 96..479 = Wv^T
      int n = r / 384, k = r % 384;
      Wkv_t[r] = f2bf(n < 96 ? Wk[k * 96 + n] : Wv[k * 384 + (n - 96)]);
    } else if ((r -= T1) < T2) {
      int n = r / 384, k = r % 384;
      Wp_t[r] = f2bf(Wp[k * 384 + n]);
    } else if ((r -= T2) < T3) {        // bias6[h][i][j] = rpb[rpi[i][j]][h]
      int h = r >> 12, ij = r & 4095;
      bias6[r] = rpb[rpi[ij] * 6 + h];
    } else {
      r -= T3;
      bias_kv[r] = (r < 96) ? bk[r] : bv[r - 96];
    }
  }
}

// ---------------------------------------------------------------- GEMM ------
// C[M=131072, N=NX*96] = A[M,384] @ Bt[N,384]^T + bias.
// BM=64 BN=96 BK=64, 40KB LDS dbuf, 4 blocks/CU, XCD-bijective swizzle.
// OUT_MODE 0: bf16 [M,96] | 2: nx==0 -> k_out[M,96]; nx>=1 -> vt_out
// (win,d,tok) bf16 with PRE-SWIZZLED 16B chunks (c ^ (d&7)).
template <int A_MODE, int OUT_MODE, int NX>
__global__ __launch_bounds__(256, 4) void gemm3_k(
    const void* __restrict__ Av, const unsigned short* __restrict__ Bt,
    const float* __restrict__ bias, void* __restrict__ Outv,
    unsigned short* __restrict__ k_out, unsigned short* __restrict__ vt_out) {
  __shared__ char lds[40960];  // A: 2x8KB @0, B: 2x12KB @16384
  constexpr int AB[2] = {0, 8192}, BB[2] = {16384, 28672};
  const int tid = threadIdx.x, lane = tid & 63, wid = tid >> 6;
  const int g = blockIdx.x;
  const int lg_id = (g & 7) * (NX * 256) + (g >> 3);
  const int my = lg_id / NX, nx = lg_id - my * NX;
  const int m0 = my * 64, n0 = nx * 96;
  const int wm = (wid >> 1) * 32, wn = (wid & 1) * 48;
  const int lr = lane & 15, lg = lane >> 4;

  float4 areg[4];
  const int ar = tid >> 2, aq = tid & 3;  // fp32-A staging: row, quarter

  auto a_issue_f32 = [&](int kt) {
    const float* A = (const float*)Av + (size_t)(m0 + ar) * 384 + kt * 64 + aq * 16;
#pragma unroll
    for (int p = 0; p < 4; ++p) areg[p] = *reinterpret_cast<const float4*>(A + p * 4);
  };
  auto a_write_f32 = [&](char* Ab) {
    unsigned pk[8];
#pragma unroll
    for (int p = 0; p < 4; ++p) {
      pk[p * 2]     = pack2(areg[p].x, areg[p].y);
      pk[p * 2 + 1] = pack2(areg[p].z, areg[p].w);
    }
    const int c0 = aq * 2;
    *reinterpret_cast<uint4*>(Ab + ar * 128 + ((c0 ^ (ar & 7)) * 16)) =
        make_uint4(pk[0], pk[1], pk[2], pk[3]);
    *reinterpret_cast<uint4*>(Ab + ar * 128 + (((c0 + 1) ^ (ar & 7)) * 16)) =
        make_uint4(pk[4], pk[5], pk[6], pk[7]);
  };
  auto b_issue = [&](int kt, char* Bb) {
#pragma unroll
    for (int j = 0; j < 3; ++j) {
      const int rb = (wid * 3 + j) * 8;
      const int row = rb + (lane >> 3), c = lane & 7;
      gl_lds16((const char*)Bt + (size_t)(n0 + row) * 768 + kt * 128 +
                   ((c ^ (row & 7)) * 16),
               Bb + rb * 128);
    }
  };

  f32x4 acc[2][3];
#pragma unroll
  for (int i = 0; i < 2; ++i)
#pragma unroll
    for (int j = 0; j < 3; ++j) acc[i][j] = (f32x4){0.f, 0.f, 0.f, 0.f};

  a_issue_f32(0);
  a_write_f32(lds + AB[0]);
  b_issue(0, lds + BB[0]);
  __syncthreads();

  int cur = 0;
  for (int kt = 0; kt < 6; ++kt) {
    char* An = lds + AB[cur ^ 1];
    char* Bn = lds + BB[cur ^ 1];
    if (kt < 5) {
      a_issue_f32(kt + 1);
      b_issue(kt + 1, Bn);
    }
    {
      const char* Ab = lds + AB[cur];
      const char* Bb = lds + BB[cur];
#pragma unroll
      for (int ks = 0; ks < 2; ++ks) {
        short8 a[2], b[3];
#pragma unroll
        for (int mf = 0; mf < 2; ++mf) {
          const int row = wm + mf * 16 + lr;
          a[mf] = *reinterpret_cast<const short8*>(
              Ab + row * 128 + (((ks * 4 + lg) ^ (row & 7)) * 16));
        }
#pragma unroll
        for (int nf = 0; nf < 3; ++nf) {
          const int row = wn + nf * 16 + lr;
          b[nf] = *reinterpret_cast<const short8*>(
              Bb + row * 128 + (((ks * 4 + lg) ^ (row & 7)) * 16));
        }
#pragma unroll
        for (int mf = 0; mf < 2; ++mf)
#pragma unroll
          for (int nf = 0; nf < 3; ++nf)
            acc[mf][nf] = mfma_b16(a[mf], b[nf], acc[mf][nf]);
      }
    }
    if (kt < 5) a_write_f32(An);
    __syncthreads();
    cur ^= 1;
  }

  // ---- epilogues
  if (OUT_MODE == 0 || (OUT_MODE == 2 && nx == 0)) {  // bf16 [M,96], pad 208
    unsigned short* dst = (OUT_MODE == 0) ? (unsigned short*)Outv : k_out;
#pragma unroll
    for (int mf = 0; mf < 2; ++mf)
#pragma unroll
      for (int nf = 0; nf < 3; ++nf) {
        const int col = wn + nf * 16 + lr;
        const float bb = bias[col];
#pragma unroll
        for (int r = 0; r < 4; ++r) {
          const int row = wm + mf * 16 + lg * 4 + r;
          *reinterpret_cast<unsigned short*>(lds + row * 208 + col * 2) =
              f2bf(acc[mf][nf][r] + bb);
        }
      }
    __syncthreads();
#pragma unroll
    for (int j = 0; j < 3; ++j) {
      const int Lb = (j * 256 + tid) * 16;
      const int row = Lb / 192, inner = Lb % 192;
      *reinterpret_cast<uint4*>((char*)dst + (size_t)(m0 + row) * 192 + inner) =
          *reinterpret_cast<const uint4*>(lds + row * 208 + inner);
    }
  } else {  // vt: transpose to (win=my, d, tok), PRE-SWIZZLED chunks
#pragma unroll
    for (int mf = 0; mf < 2; ++mf)
#pragma unroll
      for (int nf = 0; nf < 3; ++nf) {
        const int dl = wn + nf * 16 + lr;
        const float bb = bias[n0 + dl];
        const int tok0 = wm + mf * 16 + lg * 4;
        *reinterpret_cast<unsigned*>(lds + dl * 144 + tok0 * 2) =
            pack2(acc[mf][nf][0] + bb, acc[mf][nf][1] + bb);
        *reinterpret_cast<unsigned*>(lds + dl * 144 + tok0 * 2 + 4) =
            pack2(acc[mf][nf][2] + bb, acc[mf][nf][3] + bb);
      }
    __syncthreads();
#pragma unroll
    for (int j = 0; j < 3; ++j) {
      const int Lc = j * 256 + tid;  // 16B chunk id, 768 total
      const int dl = Lc >> 3, c = Lc & 7;
      *reinterpret_cast<uint4*>((char*)vt_out + (size_t)my * 49152 +
                                (size_t)((nx - 1) * 96 + dl) * 128 +
                                ((c ^ (dl & 7)) << 4)) =
          *reinterpret_cast<const uint4*>(lds + dl * 144 + c * 16);
    }
  }
}

// ------------------------------------------- fused attention + proj ---------
// 1 block = 1 window, 4 waves. LDS: vt 48KB @0 (att overlays after attn);
// P @49152 (8KB); proj B dbuf @57344 (2x12KB). 80KB total, 2 blocks/CU.
__global__ __launch_bounds__(256, 2) void ap_k(
    const unsigned short* __restrict__ q_buf, const unsigned short* __restrict__ k_buf,
    const unsigned short* __restrict__ vt_buf, const float* __restrict__ bias6,
    const float* __restrict__ mask, const unsigned short* __restrict__ Wp_t,
    const float* __restrict__ bp, float* __restrict__ out) {
  __shared__ char lds[81920];
  const int tid = threadIdx.x, lane = tid & 63, wid = tid >> 6;
  const int lr = lane & 15, lg = lane >> 4;
  const int w = blockIdx.x;

  auto b_issue = [&](int T, char* Bb) {  // T = nc*6+kt over Wp_t
    const int nc = T / 6, kt = T - nc * 6;
#pragma unroll
    for (int j = 0; j < 3; ++j) {
      const int rb = (wid * 3 + j) * 8;
      const int row = rb + (lane >> 3), c = lane & 7;
      gl_lds16((const char*)Wp_t + (size_t)(nc * 96 + row) * 768 + kt * 128 +
                   ((c ^ (row & 7)) * 16),
               Bb + rb * 128);
    }
  };

  // stage vt (pre-swizzled) + prefetch proj B tiles 0,1
  const char* vsrc = (const char*)vt_buf + (size_t)w * 49152;
#pragma unroll
  for (int j = 0; j < 12; ++j) {
    const int off = (wid * 12 + j) * 1024;
    gl_lds16(vsrc + off + lane * 16, lds + off);
  }
  b_issue(0, lds + 57344);
  b_issue(1, lds + 57344 + 12288);
  __syncthreads();

  // ---- attention; att -> stash regs
  unsigned stash[48];
  char* Plds = lds + 49152;
  const float* mw = mask + (size_t)(w & 1023) * 4096;
  const int iq = wid * 16 + lr;

  for (int h = 0; h < 6; ++h) {
    short8 qa = {0, 0, 0, 0, 0, 0, 0, 0};
    if (lg < 2)
      qa = *reinterpret_cast<const short8*>(
          q_buf + (size_t)(w * 64 + iq) * 96 + h * 16 + lg * 8);
    float sv[4][4];
#pragma unroll
    for (int tj = 0; tj < 4; ++tj) {
      short8 kf = {0, 0, 0, 0, 0, 0, 0, 0};
      if (lg < 2)
        kf = *reinterpret_cast<const short8*>(
            k_buf + (size_t)(w * 64 + tj * 16 + lr) * 96 + h * 16 + lg * 8);
      f32x4 z = {0.f, 0.f, 0.f, 0.f};
      f32x4 s = mfma_b16(kf, qa, z);
      const int j0 = tj * 16 + lg * 4;
      const float4 bi = *reinterpret_cast<const float4*>(bias6 + h * 4096 + iq * 64 + j0);
      const float4 mk = *reinterpret_cast<const float4*>(mw + iq * 64 + j0);
      sv[tj][0] = s[0] * 0.25f + bi.x + mk.x;
      sv[tj][1] = s[1] * 0.25f + bi.y + mk.y;
      sv[tj][2] = s[2] * 0.25f + bi.z + mk.z;
      sv[tj][3] = s[3] * 0.25f + bi.w + mk.w;
    }
    float mx = sv[0][0];
#pragma unroll
    for (int tj = 0; tj < 4; ++tj)
#pragma unroll
      for (int r = 0; r < 4; ++r) mx = fmaxf(mx, sv[tj][r]);
    mx = fmaxf(mx, __shfl_xor(mx, 16));
    mx = fmaxf(mx, __shfl_xor(mx, 32));
    float sum = 0.f;
#pragma unroll
    for (int tj = 0; tj < 4; ++tj)
#pragma unroll
      for (int r = 0; r < 4; ++r) {
        sv[tj][r] = __expf(sv[tj][r] - mx);
        sum += sv[tj][r];
      }
    sum += __shfl_xor(sum, 16);
    sum += __shfl_xor(sum, 32);
    const float inv = 1.0f / sum;
#pragma unroll
    for (int tj = 0; tj < 4; ++tj) {
      const int c = tj * 2 + (lg >> 1);
      uint2 st;
      st.x = pack2(sv[tj][0] * inv, sv[tj][1] * inv);
      st.y = pack2(sv[tj][2] * inv, sv[tj][3] * inv);
      *reinterpret_cast<uint2*>(Plds + iq * 128 + ((c ^ (iq & 7)) << 4) +
                                (lg & 1) * 8) = st;
    }
    short8 pa[2];
#pragma unroll
    for (int ks = 0; ks < 2; ++ks)
      pa[ks] = *reinterpret_cast<const short8*>(
          Plds + iq * 128 + (((ks * 4 + lg) ^ (iq & 7)) << 4));
#pragma unroll
    for (int td = 0; td < 4; ++td) {
      f32x4 o = {0.f, 0.f, 0.f, 0.f};
#pragma unroll
      for (int ks = 0; ks < 2; ++ks) {
        const int d = h * 64 + td * 16 + lr;
        short8 vb = *reinterpret_cast<const short8*>(
            lds + d * 128 + (((ks * 4 + lg) ^ (d & 7)) << 4));
        o = mfma_b16(vb, pa[ks], o);
      }
      stash[h * 8 + td * 2 + 0] = pack2(o[0], o[1]);
      stash[h * 8 + td * 2 + 1] = pack2(o[2], o[3]);
    }
  }
  __syncthreads();  // all vt/P reads done

  // spill att -> LDS [tok][384] bf16, swz48 chunk layout
#pragma unroll
  for (int h = 0; h < 6; ++h)
#pragma unroll
    for (int td = 0; td < 4; ++td)
#pragma unroll
      for (int p2 = 0; p2 < 2; ++p2) {
        const int c0 = h * 64 + td * 16 + lg * 4 + p2 * 2;
        *reinterpret_cast<unsigned*>(
            lds + iq * 768 + swz48(c0 >> 3, iq) * 16 + ((c0 * 2) & 15)) =
            stash[h * 8 + td * 2 + p2];
      }
  __syncthreads();

  // ---- proj: out = att @ Wp^T + bp.  24 tiles (nc,kt), B dbuf, A from LDS.
  const int wm = (wid >> 1) * 32, wn = (wid & 1) * 48;
  f32x4 acc[2][3];
#pragma unroll
  for (int i = 0; i < 2; ++i)
#pragma unroll
    for (int j = 0; j < 3; ++j) acc[i][j] = (f32x4){0.f, 0.f, 0.f, 0.f};

  for (int T = 0; T < 24; ++T) {
    const int nc = T / 6, kt = T - nc * 6;
    if (T >= 1 && T < 23) b_issue(T + 1, lds + 57344 + ((T + 1) & 1) * 12288);
    const char* Bb = lds + 57344 + (T & 1) * 12288;
#pragma unroll
    for (int ks = 0; ks < 2; ++ks) {
      short8 a[2], b[3];
#pragma unroll
      for (int mf = 0; mf < 2; ++mf) {
        const int row = wm + mf * 16 + lr;
        a[mf] = *reinterpret_cast<const short8*>(
            lds + row * 768 + swz48(kt * 8 + ks * 4 + lg, row) * 16);
      }
#pragma unroll
      for (int nf = 0; nf < 3; ++nf) {
        const int row = wn + nf * 16 + lr;
        b[nf] = *reinterpret_cast<const short8*>(
            Bb + row * 128 + (((ks * 4 + lg) ^ (row & 7)) * 16));
      }
#pragma unroll
      for (int mf = 0; mf < 2; ++mf)
#pragma unroll
        for (int nf = 0; nf < 3; ++nf)
          acc[mf][nf] = mfma_b16(a[mf], b[nf], acc[mf][nf]);
    }
    if (kt == 5) {  // epilogue for this nc, then reset acc
#pragma unroll
      for (int mf = 0; mf < 2; ++mf)
#pragma unroll
        for (int nf = 0; nf < 3; ++nf) {
          const int col = nc * 96 + wn + nf * 16 + lr;
          const float bb = bp[col];
#pragma unroll
          for (int r = 0; r < 4; ++r) {
            const int row = wm + mf * 16 + lg * 4 + r;
            out[(size_t)(w * 64 + row) * 384 + col] = acc[mf][nf][r] + bb;
          }
          acc[mf][nf] = (f32x4){0.f, 0.f, 0.f, 0.f};
        }
    }
    __syncthreads();
  }
}

// -------------------------------------------------------------- launch ------
extern "C" void kernel_launch(void* const* d_in, const int* in_sizes, int n_in,
                              void* d_out, int out_size, void* d_ws, size_t ws_size,
                              hipStream_t stream) {
  const float* x    = (const float*)d_in[0];
  const float* cx   = (const float*)d_in[1];
  const int*   rpi  = (const int*)d_in[2];
  const float* mask = (const float*)d_in[3];
  const float* Wq   = (const float*)d_in[4];
  const float* bq   = (const float*)d_in[5];
  const float* Wk   = (const float*)d_in[6];
  const float* bk   = (const float*)d_in[7];
  const float* Wv   = (const float*)d_in[8];
  const float* bv   = (const float*)d_in[9];
  const float* Wp   = (const float*)d_in[10];
  const float* bp   = (const float*)d_in[11];
  const float* rpb  = (const float*)d_in[12];

  char* ws = (char*)d_ws;
  unsigned short* Wq_t   = (unsigned short*)(ws + 0);        //  73,728 B
  unsigned short* Wkv_t  = (unsigned short*)(ws + 73728);    // 368,640 B
  unsigned short* Wp_t   = (unsigned short*)(ws + 442368);   // 294,912 B
  float*          bias6  = (float*)(ws + 737280);            //  98,304 B
  float*          biaskv = (float*)(ws + 835584);            //   1,920 B
  const size_t MB = 1u << 20;
  unsigned short* q_buf  = (unsigned short*)(ws + MB);                   // 25,165,824 B
  unsigned short* k_buf  = (unsigned short*)(ws + MB + 25165824u);       // 25,165,824 B
  unsigned short* vt_buf = (unsigned short*)(ws + MB + 50331648u);       // 100,663,296 B

  prep_k<<<256, 256, 0, stream>>>(Wq, Wk, Wv, Wp, rpb, rpi, bk, bv,
                                  Wq_t, Wkv_t, Wp_t, bias6, biaskv);
  gemm3_k<0, 0, 1><<<2048, 256, 0, stream>>>(x, Wq_t, bq, q_buf, nullptr, nullptr);
  gemm3_k<0, 2, 5><<<10240, 256, 0, stream>>>(cx, Wkv_t, biaskv, nullptr, k_buf, vt_buf);
  ap_k<<<2048, 256, 0, stream>>>(q_buf, k_buf, vt_buf, bias6, mask, Wp_t, bp,
                                 (float*)d_out);
}